// Round 5
// baseline (214.436 us; speedup 1.0000x reference)
//
#include <hip/hip_runtime.h>

// YOLO loss: preds (B,7,7,30) f32, labels (B,7,7,30) f32 -> scalar f32 (sum/B).
// R6: combine R4's coalesced global_load_lds staging with R5's pipelining.
// Post-mortem: R5 (direct strided float2 loads) was transaction-rate bound:
// 30 loads/thread x 64 distinct lines/instr ~ 3840 line-transactions per wave
// -> 49 waves/CU x 3840 ~ 188k cyc ~ 78us, matching the measured 74.7us with
// all pipes idle. R4 (block-wide LDS staging) was coalesced (240 trans/wave)
// but convoy-bound: 61KB LDS -> 2 blocks/CU, all waves drain vmcnt(0) at one
// barrier. R6: 1-wave blocks each DMA-stage their own 64-cell tile (15.9KB
// LDS -> 10 blocks/CU, barriers are wave-local waitcnts, no convoy), 4 tiles
// per block so partials stays 3136 floats (proven workspace size).
// Reduction replays R4's exact tree -> bit-identical partials, absmax 0.0.

#define BATCH 16384
#define S 7
#define C 30
#define NCELLS (BATCH * S * S)      // 802816
#define BLOCK 64                    // 1 wave per block
#define TILES 4
#define CELLS_PER_TILE 64
#define CELLS_PER_BLOCK (TILES * CELLS_PER_TILE)   // 256
#define NBLK (NCELLS / CELLS_PER_BLOCK)            // 3136

// LDS float layout (per block):
//   [0,    1920) labels, fully linear (floats 0..1919 of the tile)
//   [1920, 2048) preds tail floats 1792..1919 (DMA scratch landing zone)
//   [2048, 3968) preds, linear; [3840,3968) filled by the fixup copy
#define SL_OFF   0
#define TAILP_OFF 1920
#define SP_OFF   2048
#define LDS_FLOATS 3968             // 15872 B -> 10 blocks/CU

#define GLOBAL_LOAD_LDS16(g, l)                                         \
    __builtin_amdgcn_global_load_lds(                                   \
        (const __attribute__((address_space(1))) void*)(g),             \
        (__attribute__((address_space(3))) void*)(l), 16, 0, 0)

__device__ __forceinline__ float sq(float v) { return v * v; }

__device__ __forceinline__ float iou_box(float acx, float acy, float aw, float ah,
                                         float bcx, float bcy, float bw, float bh) {
    float ax0 = acx - aw * 0.5f, ax1 = acx + aw * 0.5f;
    float ay0 = acy - ah * 0.5f, ay1 = acy + ah * 0.5f;
    float bx0 = bcx - bw * 0.5f, bx1 = bcx + bw * 0.5f;
    float by0 = bcy - bh * 0.5f, by1 = bcy + bh * 0.5f;
    float iw = fmaxf(fminf(ax1, bx1) - fmaxf(ax0, bx0), 0.0f);
    float ih = fmaxf(fminf(ay1, by1) - fmaxf(ay0, by0), 0.0f);
    float inter = iw * ih;
    float denom = aw * ah + bw * bh - inter + 1e-10f;
    return inter / denom;
}

__global__ __launch_bounds__(BLOCK) void yolo_partial_kernel(
        const float* __restrict__ preds,
        const float* __restrict__ labels,
        float* __restrict__ partials) {
    __shared__ __align__(16) float lds[LDS_FLOATS];

    const int tid = threadIdx.x;      // == lane (1 wave per block)
    float tsum[TILES];

    #pragma unroll
    for (int t = 0; t < TILES; ++t) {
        const int base_cell = blockIdx.x * CELLS_PER_BLOCK + t * CELLS_PER_TILE;
        const float4* gp = reinterpret_cast<const float4*>(preds  + (size_t)base_cell * C);
        const float4* gl = reinterpret_cast<const float4*>(labels + (size_t)base_cell * C);

        // ensure previous tile's LDS reads retired before DMA overwrites
        __syncthreads();

        // ---- coalesced DMA staging: 15 x 1KB rounds per tile ----
        #pragma unroll
        for (int k = 0; k < 7; ++k)   // labels floats [0,1792) -> lds [0,1792)
            GLOBAL_LOAD_LDS16(gl + k * 64 + tid, (char*)lds + (size_t)k * 1024);
        #pragma unroll
        for (int k = 0; k < 7; ++k)   // preds floats [0,1792) -> lds [2048,3840)
            GLOBAL_LOAD_LDS16(gp + k * 64 + tid,
                              (char*)lds + (size_t)SP_OFF * 4 + (size_t)k * 1024);
        {   // mixed tail round: lanes 0-31 labels f4 448+l -> lds floats [1792,1920)
            //                   lanes 32-63 preds  f4 448+(l-32) -> lds floats [1920,2048)
            const float4* src = (tid < 32) ? (gl + 448 + tid) : (gp + 448 + (tid - 32));
            GLOBAL_LOAD_LDS16(src, (char*)lds + 7168);   // base = float 1792
        }

        // transposed label x-coord quirk: labels[b, x, y, 0] — independent
        // global gather, issued before the drain so it overlaps the DMA.
        const int cell = base_cell + tid;
        const int b    = cell / (S * S);
        const int rem  = cell - b * (S * S);
        const int y    = rem / S;
        const int x    = rem - y * S;
        const int pc   = b * (S * S) + x * S + y;
        const float lb0 = labels[(size_t)pc * C];

        __syncthreads();   // vmcnt drain (wave-local; 1-wave block)

        // fixup: move preds tail from scratch [1920,2048) to linear [3840,3968)
        {
            float2 v = *reinterpret_cast<const float2*>(&lds[TAILP_OFF + 2 * tid]);
            *reinterpret_cast<float2*>(&lds[SP_OFF + 1792 + 2 * tid]) = v;
        }
        __syncthreads();

        // ---- per-cell compute from LDS ----
        const float* p = &lds[SP_OFF + tid * C];
        const float* l = &lds[SL_OFF + tid * C];
        float pv[C], lv[C];
        #pragma unroll
        for (int i = 0; i < C / 2; ++i) {
            float2 tp = *reinterpret_cast<const float2*>(p + 2 * i);
            pv[2 * i] = tp.x; pv[2 * i + 1] = tp.y;
            float2 tl = *reinterpret_cast<const float2*>(l + 2 * i);
            lv[2 * i] = tl.x; lv[2 * i + 1] = tl.y;
        }

        float iou1 = iou_box(pv[0], pv[1], pv[2], pv[3], lb0, lv[1], lv[2], lv[3]);
        float iou2 = iou_box(pv[5], pv[6], pv[7], pv[8], lb0, lv[1], lv[2], lv[3]);

        float b1 = 5.0f * (sq(pv[0] - lv[0]) + sq(pv[1] - lv[1]))
                 + sq(sqrtf(pv[2]) - sqrtf(lv[2])) + sq(sqrtf(pv[3]) - sqrtf(lv[3]))
                 + sq(iou1 - pv[4])
                 + 0.5f * pv[9] * pv[9];

        float b2 = 5.0f * (sq(pv[5] - lv[5]) + sq(pv[6] - lv[6]))
                 + sq(sqrtf(pv[7]) - sqrtf(lv[7])) + sq(sqrtf(pv[8]) - sqrtf(lv[8]))
                 + sq(iou2 - pv[9])
                 + 0.5f * pv[4] * pv[4];

        float cls = 0.0f;
        #pragma unroll
        for (int c = 10; c < C; ++c) cls += sq(lv[c] - pv[c]);

        float obj_loss   = ((iou1 > iou2) ? b1 : b2) + cls;
        float noobj_loss = 0.5f * (pv[4] * pv[4] + pv[9] * pv[9]);
        float loss = (lv[4] == 1.0f) ? obj_loss : noobj_loss;

        // per-tile shuffle tree == R4's per-wave tree (bit-identical order)
        #pragma unroll
        for (int off = 32; off > 0; off >>= 1)
            loss += __shfl_down(loss, off, 64);
        tsum[t] = loss;    // valid on lane 0
    }

    if (tid == 0) {
        // same order as R4's wsum[0]+wsum[1]+wsum[2]+wsum[3]
        partials[blockIdx.x] = ((tsum[0] + tsum[1]) + tsum[2]) + tsum[3];
    }
}

__global__ __launch_bounds__(256) void yolo_reduce_kernel(
        const float* __restrict__ partials,
        float* __restrict__ out) {
    const int tid = threadIdx.x;
    float s = 0.0f;
    for (int i = tid; i < NBLK; i += 256) s += partials[i];

    #pragma unroll
    for (int off = 32; off > 0; off >>= 1)
        s += __shfl_down(s, off, 64);

    __shared__ float wsum[4];
    int lane = tid & 63;
    int wv   = tid >> 6;
    if (lane == 0) wsum[wv] = s;
    __syncthreads();
    if (tid == 0) {
        out[0] = (wsum[0] + wsum[1] + wsum[2] + wsum[3]) * (1.0f / (float)BATCH);
    }
}

extern "C" void kernel_launch(void* const* d_in, const int* in_sizes, int n_in,
                              void* d_out, int out_size, void* d_ws, size_t ws_size,
                              hipStream_t stream) {
    const float* preds  = (const float*)d_in[0];
    const float* labels = (const float*)d_in[1];
    float* out = (float*)d_out;
    float* partials = (float*)d_ws;   // NBLK floats = 12.25 KB (same as R4)

    yolo_partial_kernel<<<NBLK, BLOCK, 0, stream>>>(preds, labels, partials);
    yolo_reduce_kernel<<<1, 256, 0, stream>>>(partials, out);
}

// Round 6
// 205.405 us; speedup vs baseline: 1.0440x; 1.0440x over previous
//
#include <hip/hip_runtime.h>

// YOLO loss: preds (B,7,7,30) f32, labels (B,7,7,30) f32 -> scalar f32 (sum/B).
// R7: isolate ONE variable vs R4 (best so far, 72.4us): remove the block-wide
// vmcnt(0) convoy. Evidence: R4/R5/R6 (three maximally different structures,
// occupancy 15-60%, transactions 8x apart) all deliver 2.5-2.65 TB/s with all
// pipes idle -> suspected memory-system ceiling. R4 still has all 4 waves
// draining at one __syncthreads; R7 gives each wave a PRIVATE 64-cell staging
// region + per-wave inline-asm vmcnt(0) drain (wave-private counter), no
// cross-wave barrier until the final 16B wsum reduction. lb0 partner gather
// comes from global, issued before the drain to overlap DMA. Residency equals
// R4 (62KB LDS -> 2 blocks/CU). Reduction tree bit-identical to R4.
// If this is flat too, the 2.6 TB/s ceiling is structural -> roofline.

#define BATCH 16384
#define S 7
#define C 30
#define NCELLS (BATCH * S * S)      // 802816
#define BLOCK 256
#define CELLS_PER_BLOCK 256
#define NBLK (NCELLS / CELLS_PER_BLOCK)   // 3136

// LDS float layout (per block), per-wave private regions:
//   labels: wave w at [w*2048, w*2048+1920); [+1920,+2048) = preds-tail scratch
//   preds : wave w at [8192 + w*1920, +1792) staged, [+1792,+1920) via fixup
#define SP_BASE 8192
#define LDS_FLOATS (8192 + 4 * 1920)      // 15872 floats = 63488 B -> 2 blk/CU

#define GLOBAL_LOAD_LDS16(g, l)                                         \
    __builtin_amdgcn_global_load_lds(                                   \
        (const __attribute__((address_space(1))) void*)(g),             \
        (__attribute__((address_space(3))) void*)(l), 16, 0, 0)

__device__ __forceinline__ float sq(float v) { return v * v; }

__device__ __forceinline__ float iou_box(float acx, float acy, float aw, float ah,
                                         float bcx, float bcy, float bw, float bh) {
    float ax0 = acx - aw * 0.5f, ax1 = acx + aw * 0.5f;
    float ay0 = acy - ah * 0.5f, ay1 = acy + ah * 0.5f;
    float bx0 = bcx - bw * 0.5f, bx1 = bcx + bw * 0.5f;
    float by0 = bcy - bh * 0.5f, by1 = bcy + bh * 0.5f;
    float iw = fmaxf(fminf(ax1, bx1) - fmaxf(ax0, bx0), 0.0f);
    float ih = fmaxf(fminf(ay1, by1) - fmaxf(ay0, by0), 0.0f);
    float inter = iw * ih;
    float denom = aw * ah + bw * bh - inter + 1e-10f;
    return inter / denom;
}

__global__ __launch_bounds__(BLOCK) void yolo_partial_kernel(
        const float* __restrict__ preds,
        const float* __restrict__ labels,
        float* __restrict__ partials) {
    __shared__ __align__(16) float lds[LDS_FLOATS];
    __shared__ float wsum[4];

    const int tid  = threadIdx.x;
    const int lane = tid & 63;
    const int wv   = tid >> 6;
    const int cell0 = blockIdx.x * CELLS_PER_BLOCK + wv * 64;  // wave's 64 cells

    const float4* gp = reinterpret_cast<const float4*>(preds  + (size_t)cell0 * C);
    const float4* gl = reinterpret_cast<const float4*>(labels + (size_t)cell0 * C);
    float* sl = &lds[wv * 2048];            // labels region + tail scratch
    float* sp = &lds[SP_BASE + wv * 1920];  // preds region

    // ---- per-wave DMA staging: 15 x 1KB rounds, wave-private ----
    #pragma unroll
    for (int k = 0; k < 7; ++k)   // labels floats [0,1792)
        GLOBAL_LOAD_LDS16(gl + k * 64 + lane, (char*)sl + (size_t)k * 1024);
    #pragma unroll
    for (int k = 0; k < 7; ++k)   // preds floats [0,1792)
        GLOBAL_LOAD_LDS16(gp + k * 64 + lane, (char*)sp + (size_t)k * 1024);
    {   // mixed tail: lanes 0-31 labels f4 448+l -> sl floats [1792,1920)
        //             lanes 32-63 preds  f4 448+(l-32) -> sl floats [1920,2048)
        const float4* src = (lane < 32) ? (gl + 448 + lane) : (gp + 448 + (lane - 32));
        GLOBAL_LOAD_LDS16(src, (char*)sl + 7168);
    }

    // transposed label x-coord quirk: labels[b, x, y, 0] — independent global
    // gather issued before the drain so it overlaps the DMA in flight.
    const int cell = cell0 + lane;
    const int b    = cell / (S * S);
    const int rem  = cell - b * (S * S);
    const int y    = rem / S;
    const int x    = rem - y * S;
    const int pc   = b * (S * S) + x * S + y;
    const float lb0 = labels[(size_t)pc * C];

    // wave-private drain: waits only this wave's DMAs (+ lb0), no barrier
    asm volatile("s_waitcnt vmcnt(0)" ::: "memory");
    __builtin_amdgcn_sched_barrier(0);

    // fixup: preds tail from scratch sl[1920,2048) -> linear sp[1792,1920)
    {
        float2 v = *reinterpret_cast<const float2*>(&sl[1920 + 2 * lane]);
        *reinterpret_cast<float2*>(&sp[1792 + 2 * lane]) = v;
    }

    // ---- per-cell compute from LDS (wave-private region) ----
    const float* p = sp + lane * C;
    const float* l = sl + lane * C;
    float pv[C], lv[C];
    #pragma unroll
    for (int i = 0; i < C / 2; ++i) {
        float2 tp = *reinterpret_cast<const float2*>(p + 2 * i);
        pv[2 * i] = tp.x; pv[2 * i + 1] = tp.y;
        float2 tl = *reinterpret_cast<const float2*>(l + 2 * i);
        lv[2 * i] = tl.x; lv[2 * i + 1] = tl.y;
    }

    float iou1 = iou_box(pv[0], pv[1], pv[2], pv[3], lb0, lv[1], lv[2], lv[3]);
    float iou2 = iou_box(pv[5], pv[6], pv[7], pv[8], lb0, lv[1], lv[2], lv[3]);

    float b1 = 5.0f * (sq(pv[0] - lv[0]) + sq(pv[1] - lv[1]))
             + sq(sqrtf(pv[2]) - sqrtf(lv[2])) + sq(sqrtf(pv[3]) - sqrtf(lv[3]))
             + sq(iou1 - pv[4])
             + 0.5f * pv[9] * pv[9];

    float b2 = 5.0f * (sq(pv[5] - lv[5]) + sq(pv[6] - lv[6]))
             + sq(sqrtf(pv[7]) - sqrtf(lv[7])) + sq(sqrtf(pv[8]) - sqrtf(lv[8]))
             + sq(iou2 - pv[9])
             + 0.5f * pv[4] * pv[4];

    float cls = 0.0f;
    #pragma unroll
    for (int c = 10; c < C; ++c) cls += sq(lv[c] - pv[c]);

    float obj_loss   = ((iou1 > iou2) ? b1 : b2) + cls;
    float noobj_loss = 0.5f * (pv[4] * pv[4] + pv[9] * pv[9]);
    float loss = (lv[4] == 1.0f) ? obj_loss : noobj_loss;

    // ---- reduction: identical tree/order to R4 -> bit-identical partials ----
    #pragma unroll
    for (int off = 32; off > 0; off >>= 1)
        loss += __shfl_down(loss, off, 64);

    if (lane == 0) wsum[wv] = loss;
    __syncthreads();      // only block-wide sync in the kernel (16B exchange)
    if (tid == 0) {
        partials[blockIdx.x] = wsum[0] + wsum[1] + wsum[2] + wsum[3];
    }
}

__global__ __launch_bounds__(256) void yolo_reduce_kernel(
        const float* __restrict__ partials,
        float* __restrict__ out) {
    const int tid = threadIdx.x;
    float s = 0.0f;
    for (int i = tid; i < NBLK; i += 256) s += partials[i];

    #pragma unroll
    for (int off = 32; off > 0; off >>= 1)
        s += __shfl_down(s, off, 64);

    __shared__ float wsum[4];
    int lane = tid & 63;
    int wv   = tid >> 6;
    if (lane == 0) wsum[wv] = s;
    __syncthreads();
    if (tid == 0) {
        out[0] = (wsum[0] + wsum[1] + wsum[2] + wsum[3]) * (1.0f / (float)BATCH);
    }
}

extern "C" void kernel_launch(void* const* d_in, const int* in_sizes, int n_in,
                              void* d_out, int out_size, void* d_ws, size_t ws_size,
                              hipStream_t stream) {
    const float* preds  = (const float*)d_in[0];
    const float* labels = (const float*)d_in[1];
    float* out = (float*)d_out;
    float* partials = (float*)d_ws;   // NBLK floats = 12.25 KB

    yolo_partial_kernel<<<NBLK, BLOCK, 0, stream>>>(preds, labels, partials);
    yolo_reduce_kernel<<<1, 256, 0, stream>>>(partials, out);
}